// Round 1
// baseline (314.877 us; speedup 1.0000x reference)
//
#include <hip/hip_runtime.h>

// geodesic loss: mean(acos(clip((sum(ypred*ytrue per 3x3) - 1)*0.5, -1+eps, 1-eps)))
// B = 4,194,304 samples, 9 f32 each per input. Pure streaming reduction,
// roofline = 302 MB / 6.3 TB/s ~= 48 us.

constexpr int TPB  = 256;
constexpr int NBLK = 2048;   // ~8 blocks/CU, grid-stride
constexpr float EPSF = 1e-6f;

// block-wide double reduction; result valid on thread 0
__device__ __forceinline__ double block_reduce(double v) {
    __shared__ double sm[TPB / 64];
    const int lane = threadIdx.x & 63;
    const int wid  = threadIdx.x >> 6;
    #pragma unroll
    for (int off = 32; off > 0; off >>= 1) v += __shfl_down(v, off, 64);
    if (lane == 0) sm[wid] = v;
    __syncthreads();
    if (wid == 0) {
        v = (lane < TPB / 64) ? sm[lane] : 0.0;
        #pragma unroll
        for (int off = (TPB / 64) / 2; off > 0; off >>= 1) v += __shfl_down(v, off, 64);
    }
    return v;
}

__global__ __launch_bounds__(TPB) void geo_partial(
    const float* __restrict__ a, const float* __restrict__ b,
    double* __restrict__ partial, int nsamp)
{
    const long long tid    = (long long)blockIdx.x * TPB + threadIdx.x;
    const long long stride = (long long)gridDim.x * TPB;
    double acc = 0.0;

    // each "group" = 4 consecutive samples = 36 floats = 9 aligned float4 per input
    for (long long g = tid; g * 4 < nsamp; g += stride) {
        const long long s0 = g * 4;
        const float4* pa = reinterpret_cast<const float4*>(a + s0 * 9);
        const float4* pb = reinterpret_cast<const float4*>(b + s0 * 9);

        float va[36], vb[36];
        #pragma unroll
        for (int j = 0; j < 9; ++j) {
            float4 x = pa[j];
            va[4*j+0] = x.x; va[4*j+1] = x.y; va[4*j+2] = x.z; va[4*j+3] = x.w;
        }
        #pragma unroll
        for (int j = 0; j < 9; ++j) {
            float4 y = pb[j];
            vb[4*j+0] = y.x; vb[4*j+1] = y.y; vb[4*j+2] = y.z; vb[4*j+3] = y.w;
        }

        #pragma unroll
        for (int k = 0; k < 4; ++k) {
            if (s0 + k < nsamp) {
                float dot = 0.0f;
                #pragma unroll
                for (int j = 0; j < 9; ++j) dot = fmaf(va[9*k+j], vb[9*k+j], dot);
                float c = (dot - 1.0f) * 0.5f;
                c = fminf(fmaxf(c, -1.0f + EPSF), 1.0f - EPSF);
                acc += (double)acosf(c);
            }
        }
    }

    double r = block_reduce(acc);
    if (threadIdx.x == 0) partial[blockIdx.x] = r;
}

__global__ __launch_bounds__(TPB) void geo_final(
    const double* __restrict__ partial, float* __restrict__ out,
    int n, double inv_n)
{
    double acc = 0.0;
    for (int i = threadIdx.x; i < n; i += TPB) acc += partial[i];
    double r = block_reduce(acc);
    if (threadIdx.x == 0) out[0] = (float)(r * inv_n);
}

extern "C" void kernel_launch(void* const* d_in, const int* in_sizes, int n_in,
                              void* d_out, int out_size, void* d_ws, size_t ws_size,
                              hipStream_t stream) {
    const float* a = (const float*)d_in[0];   // ypred [B,3,3] f32
    const float* b = (const float*)d_in[1];   // ytrue [B,3,3] f32
    float* out = (float*)d_out;               // scalar f32
    const int nsamp = in_sizes[0] / 9;

    double* partial = (double*)d_ws;          // NBLK doubles; every slot written every launch

    geo_partial<<<NBLK, TPB, 0, stream>>>(a, b, partial, nsamp);
    geo_final<<<1, TPB, 0, stream>>>(partial, out, NBLK, 1.0 / (double)nsamp);
}

// Round 2
// 308.631 us; speedup vs baseline: 1.0202x; 1.0202x over previous
//
#include <hip/hip_runtime.h>

// geodesic loss: mean(acos(clip((sum(ypred*ytrue per 3x3) - 1)*0.5, -1+eps, 1-eps)))
// B = 4,194,304 samples x 9 f32 per input. Streaming reduction; roofline
// 302 MB / 6.3 TB/s ~= 48 us.
//
// R1 lesson: per-thread contiguous-sample float4 loads (144B lane stride) are
// TA-bound at 1.5 TB/s. This version loads fully coalesced (lane l -> float4
// iter*63+l, 16B/lane contiguous) and resolves the 9-float sample boundaries
// in-register: lcm(4,9)=36 -> 9 lanes hold exactly 4 samples; 63 lanes = 28
// samples per wave-iteration; 2 shuffles stitch the segmented dot products.

constexpr int TPB  = 256;
constexpr int NBLK = 2048;
constexpr float EPSF = 1e-6f;

// block-wide double reduction; result valid on thread 0
__device__ __forceinline__ double block_reduce(double v) {
    __shared__ double sm[TPB / 64];
    const int lane = threadIdx.x & 63;
    const int wid  = threadIdx.x >> 6;
    #pragma unroll
    for (int off = 32; off > 0; off >>= 1) v += __shfl_down(v, off, 64);
    if (lane == 0) sm[wid] = v;
    __syncthreads();
    if (wid == 0) {
        v = (lane < TPB / 64) ? sm[lane] : 0.0;
        #pragma unroll
        for (int off = (TPB / 64) / 2; off > 0; off >>= 1) v += __shfl_down(v, off, 64);
    }
    return v;
}

__global__ __launch_bounds__(TPB) void geo_partial(
    const float* __restrict__ a, const float* __restrict__ b,
    double* __restrict__ partial, int nsamp)
{
    const int lane = threadIdx.x & 63;
    const int wid  = threadIdx.x >> 6;
    const long long gwave  = (long long)blockIdx.x * (TPB / 64) + wid;
    const long long nwaves = (long long)gridDim.x * (TPB / 64);

    // lane -> (group g of 9 lanes, rank r within group)
    const int g = lane / 9;            // 0..6 for active lanes (lane 63 inactive)
    const int r = lane - 9 * g;
    const bool active = (lane < 63);
    // lane's 4 floats are window-words 4r..4r+3; head sample = (4r)/9
    const int head = (4 * r) / 9;
    int nh = 9 * (head + 1) - 4 * r;   // #words belonging to head sample
    if (nh > 4) nh = 4;
    const bool owner = active && ((r & 1) == 0) && (r < 8); // r in {0,2,4,6}
    const int k = r >> 1;              // owner's sample index within group

    const long long total_f4 = (long long)nsamp * 9 / 4;   // 9,437,184
    const long long n_iters  = ((long long)nsamp + 27) / 28;

    const float4* a4 = reinterpret_cast<const float4*>(a);
    const float4* b4 = reinterpret_cast<const float4*>(b);

    double acc = 0.0;
    for (long long it = gwave; it < n_iters; it += nwaves) {
        const long long f4i = it * 63 + lane;   // 16B-aligned, lane-contiguous
        float4 x = make_float4(0.f, 0.f, 0.f, 0.f);
        float4 y = make_float4(0.f, 0.f, 0.f, 0.f);
        if (active && f4i < total_f4) { x = a4[f4i]; y = b4[f4i]; }

        const float p0 = x.x * y.x, p1 = x.y * y.y, p2 = x.z * y.z, p3 = x.w * y.w;
        // prefix sums (head portion) and suffix sums (tail portion)
        const float pre2 = p0 + p1, pre3 = pre2 + p2, pre4 = pre3 + p3;
        const float suf3 = p3, suf2 = p2 + p3, suf1 = p1 + suf2;
        const float pearly = (nh == 1) ? p0 : (nh == 2) ? pre2 : (nh == 3) ? pre3 : pre4;
        const float plate  = (nh == 4) ? pre4 : (nh == 1) ? suf1 : (nh == 2) ? suf2 : suf3;

        const float v1 = __shfl(plate,  lane + 1, 64);  // Plate(l+1)
        const float v2 = __shfl(pearly, lane + 2, 64);  // Pearly(l+2)

        if (owner) {
            const long long s = it * 28 + 4 * g + k;
            if (s < nsamp) {
                const float dot = plate + v1 + v2;
                float c = (dot - 1.0f) * 0.5f;
                c = fminf(fmaxf(c, -1.0f + EPSF), 1.0f - EPSF);
                acc += (double)acosf(c);
            }
        }
    }

    const double rsum = block_reduce(acc);
    if (threadIdx.x == 0) partial[blockIdx.x] = rsum;
}

__global__ __launch_bounds__(TPB) void geo_final(
    const double* __restrict__ partial, float* __restrict__ out,
    int n, double inv_n)
{
    double acc = 0.0;
    for (int i = threadIdx.x; i < n; i += TPB) acc += partial[i];
    const double r = block_reduce(acc);
    if (threadIdx.x == 0) out[0] = (float)(r * inv_n);
}

extern "C" void kernel_launch(void* const* d_in, const int* in_sizes, int n_in,
                              void* d_out, int out_size, void* d_ws, size_t ws_size,
                              hipStream_t stream) {
    const float* a = (const float*)d_in[0];   // ypred [B,3,3] f32
    const float* b = (const float*)d_in[1];   // ytrue [B,3,3] f32
    float* out = (float*)d_out;               // scalar f32
    const int nsamp = in_sizes[0] / 9;

    double* partial = (double*)d_ws;          // NBLK doubles; all written every launch

    geo_partial<<<NBLK, TPB, 0, stream>>>(a, b, partial, nsamp);
    geo_final<<<1, TPB, 0, stream>>>(partial, out, NBLK, 1.0 / (double)nsamp);
}